// Round 7
// baseline (648.642 us; speedup 1.0000x reference)
//
#include <hip/hip_runtime.h>

// EdgeBlock: out = relu(concat(node[snd], node[rcv], edge) @ w1 + b1) @ w2 + b2
// E=800000, N=50000, D=128. fp32 in/out, fp16 MFMA.
// r7 = r4 core (w1 in LDS 96KB, 2-row staged gathers, swizzled A/h buffer)
//    + 2 tiles/wave with cross-tile S-prefetch + sched_barrier-pinned issue
//    + waves_per_eu(2,2) (256-reg budget: no spill, prefetch stays live)
//    + GEMM2 B-frags loaded once per wave (reused across both tiles).

#define NE 800000
#define DD 128

typedef float f32x4v __attribute__((ext_vector_type(4)));
typedef float f32x16 __attribute__((ext_vector_type(16)));
typedef _Float16 f16x8 __attribute__((ext_vector_type(8)));
typedef _Float16 f16x4 __attribute__((ext_vector_type(4)));

__device__ __forceinline__ f16x4 cvt4(f32x4v v) {
    f16x4 r;
    r[0] = (_Float16)v[0]; r[1] = (_Float16)v[1];
    r[2] = (_Float16)v[2]; r[3] = (_Float16)v[3];
    return r;
}

// w1[384][128] -> w1t swizzled fp16: byte = col*768 + ((k*2) ^ ((col&15)<<4))   (96KB)
// w2[128][128] -> w2f fragment-major fp16: w2f[(kk2*128 + col)*8 + j] = w2[kk2*8+j][col] (32KB)
__global__ void prep_w(const float* __restrict__ w1, const float* __restrict__ w2,
                       _Float16* __restrict__ w1t, _Float16* __restrict__ w2f) {
    int i = blockIdx.x * 256 + threadIdx.x;   // 65536 total
    if (i < 384 * 128) {
        int col = i / 384;
        int k = i - col * 384;
        float v = w1[(size_t)k * 128 + col];
        int byteoff = col * 768 + ((k * 2) ^ ((col & 15) << 4));
        *(_Float16*)((char*)w1t + byteoff) = (_Float16)v;
    } else {
        int j = i - 384 * 128;                // 0..16383
        int kk2 = j >> 10;                    // 0..15
        int col = (j >> 3) & 127;
        int jj = j & 7;
        w2f[j] = (_Float16)w2[(size_t)(kk2 * 8 + jj) * 128 + col];
    }
}

// MFMA over one staged segment: 8 k-steps against w1t in LDS
#define MFMA_SEG(SEG)                                                                     \
    _Pragma("unroll")                                                                     \
    for (int kk8 = 0; kk8 < 8; kk8++) {                                                   \
        f16x8 a = *(const f16x8*)(ab + r31 * 256 + ((kk8 * 32 + g2 * 16) ^ xa));          \
        _Pragma("unroll")                                                                 \
        for (int n = 0; n < 4; n++) {                                                     \
            const int col = n * 32 + r31;                                                 \
            f16x8 b = *(const f16x8*)(lds + col * 768 +                                   \
                       ((((SEG) * 8 + kk8) * 32 + g2 * 16) ^ ((col & 15) << 4)));         \
            acc[n] = __builtin_amdgcn_mfma_f32_32x32x16_f16(a, b, acc[n], 0, 0, 0);       \
        }                                                                                 \
    }

#define WRITE_SEG(V)                                                                      \
    _Pragma("unroll")                                                                     \
    for (int i = 0; i < 16; i++) {                                                        \
        const int row = 2 * i + g2;                                                       \
        *(f16x4*)(ab + row * 256 + ((r31 * 8) ^ ((row & 15) << 4))) = cvt4(V[i]);         \
    }

__global__ __attribute__((amdgpu_flat_work_group_size(512, 512),
                          amdgpu_waves_per_eu(2, 2)))
void edge_mlp(
    const float* __restrict__ node_attr,
    const int* __restrict__ eidx,
    const float* __restrict__ edge_attr,
    const _Float16* __restrict__ w1t,   // swizzled, 96KB
    const float* __restrict__ b1,
    const _Float16* __restrict__ w2f,   // fragment-major, 32KB
    const float* __restrict__ b2,
    float* __restrict__ out) {
    extern __shared__ char lds[];   // [0,96K): w1t swz   [96K + wid*8K): A/h per wave

    const int tid = threadIdx.x;
    const int wid = tid >> 6;
    const int lane = tid & 63;
    const int r31 = lane & 31;
    const int g2 = lane >> 5;

    // ---- stage w1t -> LDS (linear copy of pre-swizzled data) ----
    {
        const char* src = (const char*)w1t;
        #pragma unroll
        for (int i = 0; i < 12; i++) {
            int off = (tid + i * 512) * 16;   // 512*12*16B = 96KB
            *(f16x8*)(lds + off) = *(const f16x8*)(src + off);
        }
    }

    float b1v[4], b2v[4];
    #pragma unroll
    for (int n = 0; n < 4; n++) { b1v[n] = b1[n * 32 + r31]; b2v[n] = b2[n * 32 + r31]; }

    __syncthreads();   // only block-wide sync; before any divergent exit

    const int ebase0 = blockIdx.x * 512 + wid * 64;   // this wave: [ebase0, ebase0+64)
    if (ebase0 >= NE) return;                          // tail waves of last block
    const int ebase1 = ebase0 + 32;

    char* ab = lds + 96 * 1024 + wid * 8192;
    const int xa = (r31 & 15) << 4;

    const int sidx0 = eidx[ebase0 + r31];
    const int ridx0 = eidx[NE + ebase0 + r31];
    const int sidx1 = eidx[ebase1 + r31];
    const int ridx1 = eidx[NE + ebase1 + r31];

    // GEMM2 B fragments: load once, reuse for both tiles (32 regs, L2-hot)
    f16x8 b2f[8][4];
    #pragma unroll
    for (int kk = 0; kk < 8; kk++)
        #pragma unroll
        for (int n = 0; n < 4; n++)
            b2f[kk][n] = *(const f16x8*)(w2f + ((size_t)((kk * 2 + g2) * 128 + n * 32 + r31)) * 8);

    // =================== TILE 0 ===================
    f32x4v sv[16], rv[16], ev[16];
    #pragma unroll
    for (int i = 0; i < 16; i++) {
        int r = __shfl(sidx0, 2 * i + g2);
        sv[i] = *(const f32x4v*)(node_attr + (size_t)r * DD + r31 * 4);
    }
    __builtin_amdgcn_sched_barrier(0);
    WRITE_SEG(sv)
    #pragma unroll
    for (int i = 0; i < 16; i++) {
        int r = __shfl(ridx0, 2 * i + g2);
        rv[i] = *(const f32x4v*)(node_attr + (size_t)r * DD + r31 * 4);
    }
    __builtin_amdgcn_sched_barrier(0);

    f32x16 acc[4] = {};
    __builtin_amdgcn_wave_barrier();
    MFMA_SEG(0)

    WRITE_SEG(rv)
    #pragma unroll
    for (int i = 0; i < 16; i++) {
        const int row = 2 * i + g2;
        ev[i] = __builtin_nontemporal_load(
            (const f32x4v*)(edge_attr + (size_t)(ebase0 + row) * DD + r31 * 4));
    }
    __builtin_amdgcn_sched_barrier(0);
    __builtin_amdgcn_wave_barrier();
    MFMA_SEG(1)

    WRITE_SEG(ev)
    __builtin_amdgcn_wave_barrier();
    MFMA_SEG(2)

    // ---- cross-tile prefetch: tile1 sender gathers fly under h0+GEMM2+store0 ----
    f32x4v sv1[16];
    #pragma unroll
    for (int i = 0; i < 16; i++) {
        int r = __shfl(sidx1, 2 * i + g2);
        sv1[i] = *(const f32x4v*)(node_attr + (size_t)r * DD + r31 * 4);
    }
    __builtin_amdgcn_sched_barrier(0);

    // ---- bias + relu, h0 -> LDS ----
    #pragma unroll
    for (int n = 0; n < 4; n++) {
        const int col = n * 32 + r31;
        #pragma unroll
        for (int reg = 0; reg < 16; reg++) {
            const int row = (reg & 3) + 8 * (reg >> 2) + 4 * g2;
            float v = fmaxf(acc[n][reg] + b1v[n], 0.0f);
            *(_Float16*)(ab + row * 256 + ((col * 2) ^ ((row & 15) << 4))) = (_Float16)v;
        }
    }
    __builtin_amdgcn_wave_barrier();

    // ---- GEMM2 tile0 ----
    {
        f32x16 acc2[4] = {};
        #pragma unroll
        for (int kk = 0; kk < 8; kk++) {
            f16x8 a = *(const f16x8*)(ab + r31 * 256 + ((kk * 32 + g2 * 16) ^ xa));
            #pragma unroll
            for (int n = 0; n < 4; n++)
                acc2[n] = __builtin_amdgcn_mfma_f32_32x32x16_f16(a, b2f[kk][n], acc2[n], 0, 0, 0);
        }
        #pragma unroll
        for (int n = 0; n < 4; n++)
            #pragma unroll
            for (int reg = 0; reg < 16; reg++) {
                const int row = (reg & 3) + 8 * (reg >> 2) + 4 * g2;
                __builtin_nontemporal_store(acc2[n][reg] + b2v[n],
                    out + (size_t)(ebase0 + row) * DD + n * 32 + r31);
            }
    }

    // =================== TILE 1 ===================
    __builtin_amdgcn_wave_barrier();
    WRITE_SEG(sv1)
    #pragma unroll
    for (int i = 0; i < 16; i++) {
        int r = __shfl(ridx1, 2 * i + g2);
        rv[i] = *(const f32x4v*)(node_attr + (size_t)r * DD + r31 * 4);
    }
    __builtin_amdgcn_sched_barrier(0);

    #pragma unroll
    for (int n = 0; n < 4; n++) acc[n] = (f32x16)(0.0f);
    __builtin_amdgcn_wave_barrier();
    MFMA_SEG(0)

    WRITE_SEG(rv)
    #pragma unroll
    for (int i = 0; i < 16; i++) {
        const int row = 2 * i + g2;
        ev[i] = __builtin_nontemporal_load(
            (const f32x4v*)(edge_attr + (size_t)(ebase1 + row) * DD + r31 * 4));
    }
    __builtin_amdgcn_sched_barrier(0);
    __builtin_amdgcn_wave_barrier();
    MFMA_SEG(1)

    WRITE_SEG(ev)
    __builtin_amdgcn_wave_barrier();
    MFMA_SEG(2)

    // ---- bias + relu, h1 -> LDS ----
    #pragma unroll
    for (int n = 0; n < 4; n++) {
        const int col = n * 32 + r31;
        #pragma unroll
        for (int reg = 0; reg < 16; reg++) {
            const int row = (reg & 3) + 8 * (reg >> 2) + 4 * g2;
            float v = fmaxf(acc[n][reg] + b1v[n], 0.0f);
            *(_Float16*)(ab + row * 256 + ((col * 2) ^ ((row & 15) << 4))) = (_Float16)v;
        }
    }
    __builtin_amdgcn_wave_barrier();

    // ---- GEMM2 tile1 ----
    {
        f32x16 acc2[4] = {};
        #pragma unroll
        for (int kk = 0; kk < 8; kk++) {
            f16x8 a = *(const f16x8*)(ab + r31 * 256 + ((kk * 32 + g2 * 16) ^ xa));
            #pragma unroll
            for (int n = 0; n < 4; n++)
                acc2[n] = __builtin_amdgcn_mfma_f32_32x32x16_f16(a, b2f[kk][n], acc2[n], 0, 0, 0);
        }
        #pragma unroll
        for (int n = 0; n < 4; n++)
            #pragma unroll
            for (int reg = 0; reg < 16; reg++) {
                const int row = (reg & 3) + 8 * (reg >> 2) + 4 * g2;
                __builtin_nontemporal_store(acc2[n][reg] + b2v[n],
                    out + (size_t)(ebase1 + row) * DD + n * 32 + r31);
            }
    }
}

extern "C" void kernel_launch(void* const* d_in, const int* in_sizes, int n_in,
                              void* d_out, int out_size, void* d_ws, size_t ws_size,
                              hipStream_t stream) {
    const float* node_attr = (const float*)d_in[0];
    const int* eidx = (const int*)d_in[1];
    const float* edge_attr = (const float*)d_in[2];
    const float* w1 = (const float*)d_in[3];
    const float* b1 = (const float*)d_in[4];
    const float* w2 = (const float*)d_in[5];
    const float* b2 = (const float*)d_in[6];
    float* out = (float*)d_out;

    _Float16* w1t = (_Float16*)d_ws;            // 96KB swizzled
    _Float16* w2f = w1t + 384 * 128;            // 32KB fragment-major

    hipFuncSetAttribute((const void*)edge_mlp,
                        hipFuncAttributeMaxDynamicSharedMemorySize, 160 * 1024);

    prep_w<<<256, 256, 0, stream>>>(w1, w2, w1t, w2f);
    edge_mlp<<<1563, 512, 160 * 1024, stream>>>(node_attr, eidx, edge_attr,
                                                w1t, b1, w2f, b2, out);
}

// Round 8
// 378.974 us; speedup vs baseline: 1.7116x; 1.7116x over previous
//
#include <hip/hip_runtime.h>

// EdgeBlock: out = relu(concat(node[snd], node[rcv], edge) @ w1 + b1) @ w2 + b2
// E=800000, N=50000, D=128. fp32 in/out, fp16 MFMA.
// r8 = r4's exact per-wave serial structure (proven: 92 VGPR, 0 spill, 0 conflicts)
//      with w1 fragment-major in global L2 instead of LDS:
//      LDS 160KB->32KB static => 5 blocks/CU = 20 waves/CU (TLP, not ILP).
//      No occupancy attributes -- default allocator handled this shape cleanly in r4.

#define NE 800000
#define DD 128

typedef float f32x4v __attribute__((ext_vector_type(4)));
typedef float f32x16 __attribute__((ext_vector_type(16)));
typedef _Float16 f16x8 __attribute__((ext_vector_type(8)));
typedef _Float16 f16x4 __attribute__((ext_vector_type(4)));

__device__ __forceinline__ f16x4 cvt4(f32x4v v) {
    f16x4 r;
    r[0] = (_Float16)v[0]; r[1] = (_Float16)v[1];
    r[2] = (_Float16)v[2]; r[3] = (_Float16)v[3];
    return r;
}

// Fragment-major weights: wf[(kk2*128 + col)*8 + j] = w[(kk2*8 + j)*128 + col]
// w1f: kk2 = 0..47 (96KB fp16), w2f: kk2 = 0..15 (32KB fp16)
__global__ void prep_w(const float* __restrict__ w1, const float* __restrict__ w2,
                       _Float16* __restrict__ w1f, _Float16* __restrict__ w2f) {
    int i = blockIdx.x * 256 + threadIdx.x;   // 65536 total
    if (i < 48 * 128 * 8) {
        int kk2 = i >> 10;
        int col = (i >> 3) & 127;
        int j = i & 7;
        w1f[i] = (_Float16)w1[(size_t)(kk2 * 8 + j) * 128 + col];
    } else {
        int t = i - 48 * 128 * 8;
        int kk2 = t >> 10;
        int col = (t >> 3) & 127;
        int j = t & 7;
        w2f[t] = (_Float16)w2[(size_t)(kk2 * 8 + j) * 128 + col];
    }
}

__global__ __launch_bounds__(256) void edge_mlp(
    const float* __restrict__ node_attr,
    const int* __restrict__ eidx,
    const float* __restrict__ edge_attr,
    const _Float16* __restrict__ w1f,   // fragment-major, 96KB (L2-resident)
    const float* __restrict__ b1,
    const _Float16* __restrict__ w2f,   // fragment-major, 32KB (L2-resident)
    const float* __restrict__ b2,
    float* __restrict__ out) {
    __shared__ _Float16 abuf[4][4096];   // 4 waves x 8KB A/h buffer = 32KB

    const int tid = threadIdx.x;
    const int wid = tid >> 6;
    const int lane = tid & 63;
    const int r31 = lane & 31;
    const int g2 = lane >> 5;
    const int sub = g2;           // row selector within gathered pair
    const int c4 = r31;           // float4 index within row

    char* ab = (char*)abuf[wid];
    const int ebase = blockIdx.x * 128 + wid * 32;

    const int sidx = eidx[ebase + r31];
    const int ridx = eidx[NE + ebase + r31];

    float b1v[4], b2v[4];
    #pragma unroll
    for (int n = 0; n < 4; n++) { b1v[n] = b1[n * 32 + r31]; b2v[n] = b2[n * 32 + r31]; }

    const int xa = (r31 & 15) << 4;   // A-read swizzle

    // ---- gather sender rows: 2 rows per instr, coalesced 128B segments ----
    f32x4v sv[16];
    #pragma unroll
    for (int i = 0; i < 16; i++) {
        int r = __shfl(sidx, 2 * i + sub);
        sv[i] = *(const f32x4v*)(node_attr + (size_t)r * DD + c4 * 4);
    }
    // write seg S to LDS (cvt f16, swizzled)
    #pragma unroll
    for (int i = 0; i < 16; i++) {
        const int row = 2 * i + sub;
        *(f16x4*)(ab + row * 256 + ((c4 * 8) ^ ((row & 15) << 4))) = cvt4(sv[i]);
    }

    // issue receiver gathers (may fly during seg-S MFMAs)
    f32x4v rv[16];
    #pragma unroll
    for (int i = 0; i < 16; i++) {
        int r = __shfl(ridx, 2 * i + sub);
        rv[i] = *(const f32x4v*)(node_attr + (size_t)r * DD + c4 * 4);
    }

    f32x16 acc[4] = {};
    __builtin_amdgcn_wave_barrier();

    // ---- consume seg 0 (sender): B from w1f (global, L2-hot, coalesced) ----
    #pragma unroll
    for (int kk8 = 0; kk8 < 8; kk8++) {
        f16x8 a = *(const f16x8*)(ab + r31 * 256 + ((kk8 * 32 + g2 * 16) ^ xa));
        const int kk = 0 * 8 + kk8;
        #pragma unroll
        for (int n = 0; n < 4; n++) {
            f16x8 b = *(const f16x8*)(w1f + ((size_t)((kk * 2 + g2) * 128 + n * 32 + r31)) * 8);
            acc[n] = __builtin_amdgcn_mfma_f32_32x32x16_f16(a, b, acc[n], 0, 0, 0);
        }
    }

    // write seg R, issue edge loads
    #pragma unroll
    for (int i = 0; i < 16; i++) {
        const int row = 2 * i + sub;
        *(f16x4*)(ab + row * 256 + ((c4 * 8) ^ ((row & 15) << 4))) = cvt4(rv[i]);
    }
    f32x4v ev[16];
    #pragma unroll
    for (int i = 0; i < 16; i++) {
        const int row = 2 * i + sub;
        ev[i] = __builtin_nontemporal_load(
            (const f32x4v*)(edge_attr + (size_t)(ebase + row) * DD + c4 * 4));
    }
    __builtin_amdgcn_wave_barrier();

    // ---- consume seg 1 (receiver) ----
    #pragma unroll
    for (int kk8 = 0; kk8 < 8; kk8++) {
        f16x8 a = *(const f16x8*)(ab + r31 * 256 + ((kk8 * 32 + g2 * 16) ^ xa));
        const int kk = 1 * 8 + kk8;
        #pragma unroll
        for (int n = 0; n < 4; n++) {
            f16x8 b = *(const f16x8*)(w1f + ((size_t)((kk * 2 + g2) * 128 + n * 32 + r31)) * 8);
            acc[n] = __builtin_amdgcn_mfma_f32_32x32x16_f16(a, b, acc[n], 0, 0, 0);
        }
    }

    // write seg E; prefetch GEMM2 B half-0
    #pragma unroll
    for (int i = 0; i < 16; i++) {
        const int row = 2 * i + sub;
        *(f16x4*)(ab + row * 256 + ((c4 * 8) ^ ((row & 15) << 4))) = cvt4(ev[i]);
    }
    f16x8 b2fa[4][4];
    #pragma unroll
    for (int kk = 0; kk < 4; kk++)
        #pragma unroll
        for (int n = 0; n < 4; n++)
            b2fa[kk][n] = *(const f16x8*)(w2f + ((size_t)((kk * 2 + g2) * 128 + n * 32 + r31)) * 8);
    __builtin_amdgcn_wave_barrier();

    // ---- consume seg 2 (edge) ----
    #pragma unroll
    for (int kk8 = 0; kk8 < 8; kk8++) {
        f16x8 a = *(const f16x8*)(ab + r31 * 256 + ((kk8 * 32 + g2 * 16) ^ xa));
        const int kk = 2 * 8 + kk8;
        #pragma unroll
        for (int n = 0; n < 4; n++) {
            f16x8 b = *(const f16x8*)(w1f + ((size_t)((kk * 2 + g2) * 128 + n * 32 + r31)) * 8);
            acc[n] = __builtin_amdgcn_mfma_f32_32x32x16_f16(a, b, acc[n], 0, 0, 0);
        }
    }

    // ---- bias + relu, h -> same LDS buffer (seg data dead) ----
    #pragma unroll
    for (int n = 0; n < 4; n++) {
        const int col = n * 32 + r31;
        #pragma unroll
        for (int reg = 0; reg < 16; reg++) {
            const int row = (reg & 3) + 8 * (reg >> 2) + 4 * g2;
            float v = fmaxf(acc[n][reg] + b1v[n], 0.0f);
            *(_Float16*)(ab + row * 256 + ((col * 2) ^ ((row & 15) << 4))) = (_Float16)v;
        }
    }
    __builtin_amdgcn_wave_barrier();

    // ---------------- GEMM2: [32x128] @ [128x128] ----------------
    f32x16 acc2[4] = {};
    #pragma unroll
    for (int kk = 0; kk < 4; kk++) {
        f16x8 a = *(const f16x8*)(ab + r31 * 256 + ((kk * 32 + g2 * 16) ^ xa));
        #pragma unroll
        for (int n = 0; n < 4; n++)
            acc2[n] = __builtin_amdgcn_mfma_f32_32x32x16_f16(a, b2fa[kk][n], acc2[n], 0, 0, 0);
    }
    f16x8 b2fb[4][4];
    #pragma unroll
    for (int kk = 0; kk < 4; kk++)
        #pragma unroll
        for (int n = 0; n < 4; n++)
            b2fb[kk][n] = *(const f16x8*)(w2f + ((size_t)(((kk + 4) * 2 + g2) * 128 + n * 32 + r31)) * 8);
    #pragma unroll
    for (int kk = 4; kk < 8; kk++) {
        f16x8 a = *(const f16x8*)(ab + r31 * 256 + ((kk * 32 + g2 * 16) ^ xa));
        #pragma unroll
        for (int n = 0; n < 4; n++)
            acc2[n] = __builtin_amdgcn_mfma_f32_32x32x16_f16(a, b2fb[kk - 4][n], acc2[n], 0, 0, 0);
    }

    // ---- bias + store fp32 (coalesced 128B lines, nontemporal) ----
    #pragma unroll
    for (int n = 0; n < 4; n++) {
        #pragma unroll
        for (int reg = 0; reg < 16; reg++) {
            const int row = (reg & 3) + 8 * (reg >> 2) + 4 * g2;
            __builtin_nontemporal_store(acc2[n][reg] + b2v[n],
                out + (size_t)(ebase + row) * DD + n * 32 + r31);
        }
    }
}

extern "C" void kernel_launch(void* const* d_in, const int* in_sizes, int n_in,
                              void* d_out, int out_size, void* d_ws, size_t ws_size,
                              hipStream_t stream) {
    const float* node_attr = (const float*)d_in[0];
    const int* eidx = (const int*)d_in[1];
    const float* edge_attr = (const float*)d_in[2];
    const float* w1 = (const float*)d_in[3];
    const float* b1 = (const float*)d_in[4];
    const float* w2 = (const float*)d_in[5];
    const float* b2 = (const float*)d_in[6];
    float* out = (float*)d_out;

    _Float16* w1f = (_Float16*)d_ws;            // 96KB fragment-major
    _Float16* w2f = w1f + 48 * 128 * 8;         // 32KB fragment-major

    prep_w<<<256, 256, 0, stream>>>(w1, w2, w1f, w2f);
    edge_mlp<<<6250, 256, 0, stream>>>(node_attr, eidx, edge_attr,
                                       w1f, b1, w2f, b2, out);
}

// Round 9
// 288.587 us; speedup vs baseline: 2.2476x; 1.3132x over previous
//
#include <hip/hip_runtime.h>

// EdgeBlock: out = relu(concat(node[snd], node[rcv], edge) @ w1 + b1) @ w2 + b2
// E=800000, N=50000, D=128. fp32 in/out, fp16 MFMA.
// r9 = r4 (272us: w1 swizzled in LDS, 2-row staged gathers, 0 conflicts)
//      + pinned prefetch: rv AND ev issued before seg0 MFMAs, sched_barrier(0)
//        prevents sinking; b2f (128 regs) issued only after ev dies.
//      Peak live ~222 regs < 256 (waves_per_eu(2,2), 8 waves/CU, 1 blk/CU @160KB).

#define NE 800000
#define DD 128

typedef float f32x4v __attribute__((ext_vector_type(4)));
typedef float f32x16 __attribute__((ext_vector_type(16)));
typedef _Float16 f16x8 __attribute__((ext_vector_type(8)));
typedef _Float16 f16x4 __attribute__((ext_vector_type(4)));

__device__ __forceinline__ f16x4 cvt4(f32x4v v) {
    f16x4 r;
    r[0] = (_Float16)v[0]; r[1] = (_Float16)v[1];
    r[2] = (_Float16)v[2]; r[3] = (_Float16)v[3];
    return r;
}

// w1[384][128] -> w1t swizzled fp16: byte = col*768 + ((k*2) ^ ((col&15)<<4))   (96KB)
// w2[128][128] -> w2f fragment-major fp16: w2f[(kk2*128 + col)*8 + j] = w2[kk2*8+j][col] (32KB)
__global__ void prep_w(const float* __restrict__ w1, const float* __restrict__ w2,
                       _Float16* __restrict__ w1t, _Float16* __restrict__ w2f) {
    int i = blockIdx.x * 256 + threadIdx.x;   // 65536 total
    if (i < 384 * 128) {
        int col = i / 384;
        int k = i - col * 384;
        float v = w1[(size_t)k * 128 + col];
        int byteoff = col * 768 + ((k * 2) ^ ((col & 15) << 4));
        *(_Float16*)((char*)w1t + byteoff) = (_Float16)v;
    } else {
        int j = i - 384 * 128;                // 0..16383
        int kk2 = j >> 10;                    // 0..15
        int col = (j >> 3) & 127;
        int jj = j & 7;
        w2f[j] = (_Float16)w2[(size_t)(kk2 * 8 + jj) * 128 + col];
    }
}

// MFMA over one staged segment: 8 k-steps against w1t in LDS
#define MFMA_SEG(SEG)                                                                     \
    _Pragma("unroll")                                                                     \
    for (int kk8 = 0; kk8 < 8; kk8++) {                                                   \
        f16x8 a = *(const f16x8*)(ab + r31 * 256 + ((kk8 * 32 + g2 * 16) ^ xa));          \
        _Pragma("unroll")                                                                 \
        for (int n = 0; n < 4; n++) {                                                     \
            const int col = n * 32 + r31;                                                 \
            f16x8 b = *(const f16x8*)(lds + col * 768 +                                   \
                       ((((SEG) * 8 + kk8) * 32 + g2 * 16) ^ ((col & 15) << 4)));         \
            acc[n] = __builtin_amdgcn_mfma_f32_32x32x16_f16(a, b, acc[n], 0, 0, 0);       \
        }                                                                                 \
    }

#define WRITE_SEG(V)                                                                      \
    _Pragma("unroll")                                                                     \
    for (int i = 0; i < 16; i++) {                                                        \
        const int row = 2 * i + g2;                                                       \
        *(f16x4*)(ab + row * 256 + ((r31 * 8) ^ ((row & 15) << 4))) = cvt4(V[i]);         \
    }

__global__ __attribute__((amdgpu_flat_work_group_size(512, 512),
                          amdgpu_waves_per_eu(2, 2)))
void edge_mlp(
    const float* __restrict__ node_attr,
    const int* __restrict__ eidx,
    const float* __restrict__ edge_attr,
    const _Float16* __restrict__ w1t,   // swizzled, 96KB
    const float* __restrict__ b1,
    const _Float16* __restrict__ w2f,   // fragment-major, 32KB
    const float* __restrict__ b2,
    float* __restrict__ out) {
    extern __shared__ char lds[];   // [0,96K): w1t swz   [96K + wid*8K): A/h per wave

    const int tid = threadIdx.x;
    const int wid = tid >> 6;
    const int lane = tid & 63;
    const int r31 = lane & 31;
    const int g2 = lane >> 5;

    // ---- stage w1t -> LDS (linear copy of pre-swizzled data) ----
    {
        const char* src = (const char*)w1t;
        #pragma unroll
        for (int i = 0; i < 12; i++) {
            int off = (tid + i * 512) * 16;   // 512*12*16B = 96KB
            *(f16x8*)(lds + off) = *(const f16x8*)(src + off);
        }
    }

    float b1v[4], b2v[4];
    #pragma unroll
    for (int n = 0; n < 4; n++) { b1v[n] = b1[n * 32 + r31]; b2v[n] = b2[n * 32 + r31]; }

    __syncthreads();

    const int ebase = blockIdx.x * 256 + wid * 32;
    char* ab = lds + 96 * 1024 + wid * 8192;
    const int xa = (r31 & 15) << 4;

    const int sidx = eidx[ebase + r31];
    const int ridx = eidx[NE + ebase + r31];

    // ---- issue sender gathers: 2 rows/instr, 128B-coalesced ----
    f32x4v sv[16];
    #pragma unroll
    for (int i = 0; i < 16; i++) {
        int r = __shfl(sidx, 2 * i + g2);
        sv[i] = *(const f32x4v*)(node_attr + (size_t)r * DD + r31 * 4);
    }
    __builtin_amdgcn_sched_barrier(0);

    // write seg S (waitcnt on sv inside)
    WRITE_SEG(sv)

    // ---- issue receiver AND edge loads; pin them before seg0 MFMAs ----
    f32x4v rv[16];
    #pragma unroll
    for (int i = 0; i < 16; i++) {
        int r = __shfl(ridx, 2 * i + g2);
        rv[i] = *(const f32x4v*)(node_attr + (size_t)r * DD + r31 * 4);
    }
    f32x4v ev[16];
    #pragma unroll
    for (int i = 0; i < 16; i++) {
        const int row = 2 * i + g2;
        ev[i] = __builtin_nontemporal_load(
            (const f32x4v*)(edge_attr + (size_t)(ebase + row) * DD + r31 * 4));
    }
    __builtin_amdgcn_sched_barrier(0);

    f32x16 acc[4] = {};
    __builtin_amdgcn_wave_barrier();

    // ---- consume seg 0 (sender); rv+ev in flight ----
    MFMA_SEG(0)

    WRITE_SEG(rv)
    __builtin_amdgcn_wave_barrier();

    // ---- consume seg 1 (receiver); ev in flight ----
    MFMA_SEG(1)

    WRITE_SEG(ev)

    // ---- issue GEMM2 B frags (128 regs; ev dead now) ----
    f16x8 b2f[8][4];
    #pragma unroll
    for (int kk = 0; kk < 8; kk++)
        #pragma unroll
        for (int n = 0; n < 4; n++)
            b2f[kk][n] = *(const f16x8*)(w2f + ((size_t)((kk * 2 + g2) * 128 + n * 32 + r31)) * 8);
    __builtin_amdgcn_sched_barrier(0);
    __builtin_amdgcn_wave_barrier();

    // ---- consume seg 2 (edge); b2f in flight ----
    MFMA_SEG(2)

    // ---- bias + relu, h -> same LDS buffer ----
    #pragma unroll
    for (int n = 0; n < 4; n++) {
        const int col = n * 32 + r31;
        #pragma unroll
        for (int reg = 0; reg < 16; reg++) {
            const int row = (reg & 3) + 8 * (reg >> 2) + 4 * g2;
            float v = fmaxf(acc[n][reg] + b1v[n], 0.0f);
            *(_Float16*)(ab + row * 256 + ((col * 2) ^ ((row & 15) << 4))) = (_Float16)v;
        }
    }
    __builtin_amdgcn_wave_barrier();

    // ---------------- GEMM2: [32x128] @ [128x128] ----------------
    f32x16 acc2[4] = {};
    #pragma unroll
    for (int kk = 0; kk < 8; kk++) {
        f16x8 a = *(const f16x8*)(ab + r31 * 256 + ((kk * 32 + g2 * 16) ^ xa));
        #pragma unroll
        for (int n = 0; n < 4; n++)
            acc2[n] = __builtin_amdgcn_mfma_f32_32x32x16_f16(a, b2f[kk][n], acc2[n], 0, 0, 0);
    }

    // ---- bias + store fp32 (coalesced 128B lines, nontemporal) ----
    #pragma unroll
    for (int n = 0; n < 4; n++) {
        #pragma unroll
        for (int reg = 0; reg < 16; reg++) {
            const int row = (reg & 3) + 8 * (reg >> 2) + 4 * g2;
            __builtin_nontemporal_store(acc2[n][reg] + b2v[n],
                out + (size_t)(ebase + row) * DD + n * 32 + r31);
        }
    }
}

extern "C" void kernel_launch(void* const* d_in, const int* in_sizes, int n_in,
                              void* d_out, int out_size, void* d_ws, size_t ws_size,
                              hipStream_t stream) {
    const float* node_attr = (const float*)d_in[0];
    const int* eidx = (const int*)d_in[1];
    const float* edge_attr = (const float*)d_in[2];
    const float* w1 = (const float*)d_in[3];
    const float* b1 = (const float*)d_in[4];
    const float* w2 = (const float*)d_in[5];
    const float* b2 = (const float*)d_in[6];
    float* out = (float*)d_out;

    _Float16* w1t = (_Float16*)d_ws;            // 96KB swizzled
    _Float16* w2f = w1t + 384 * 128;            // 32KB fragment-major

    hipFuncSetAttribute((const void*)edge_mlp,
                        hipFuncAttributeMaxDynamicSharedMemorySize, 160 * 1024);

    prep_w<<<256, 256, 0, stream>>>(w1, w2, w1t, w2f);
    edge_mlp<<<3125, 512, 160 * 1024, stream>>>(node_attr, eidx, edge_attr,
                                                w1t, b1, w2f, b2, out);
}